// Round 1
// baseline (21350.897 us; speedup 1.0000x reference)
//
#include <hip/hip_runtime.h>
#include <math.h>

#define TT 256
#define BB 256
#define DP1 129
#define HH 512
#define G3 1536
#define K1 1280
#define DD 128
#define RTOT 65280   // B*(T-1)

// ws layout (in floats)
#define OFF_WTX 0
#define OFF_WTH 198144       // 129*1536
#define OFF_W1T 984576       // +512*1536
#define OFF_W2T 1641216      // +513*1280
#define OFF_OUTS 1805056     // +1280*128
// out layout (floats)
#define OUT_DIST 8355840     // 256*255*128
#define OUT_LEN  8356608     // +256*3

__device__ __forceinline__ float sigm(float v) { return 1.0f / (1.0f + __expf(-v)); }

// Build k-major (transposed) copies of the weight matrices so GEMM-ish loops
// read W coalesced (lane = output column) and activations as wave-broadcast.
__global__ __launch_bounds__(256) void prep_kernel(
    const float* __restrict__ w_ih, const float* __restrict__ w_hh,
    const float* __restrict__ w1, const float* __restrict__ w2,
    float* __restrict__ ws)
{
    int i = blockIdx.x * 256 + threadIdx.x;
    if (i < 198144) {                       // wTx[k][j] = w_ih[j][k]
        int k = i / G3, j = i - k * G3;
        ws[OFF_WTX + i] = w_ih[j * DP1 + k];
    } else if (i < 984576) {                // wTh[k][j] = w_hh[j][k]
        int r = i - 198144;
        int k = r / G3, j = r - k * G3;
        ws[OFF_WTH + r] = w_hh[j * HH + k];
    } else if (i < 1641216) {               // w1T[k][kc] = w1[kc][k]
        int r = i - 984576;
        int k = r / K1, kc = r - k * K1;
        ws[OFF_W1T + r] = w1[kc * 513 + k];
    } else if (i < 1805056) {               // w2T[kc][d] = w2[d][kc]
        int r = i - 1641216;
        int kc = r / DD, d = r - kc * DD;
        ws[OFF_W2T + r] = w2[d * K1 + kc];
    }
}

// One GRU timestep, fully fused: xw (K=129) + hw (K=512) + gates + carry.
// grid (16 row-blocks, 16 col-blocks), 256 threads; thread = 1 batch row x 2 h-cols.
__global__ __launch_bounds__(256) void gru_step(
    const float* __restrict__ x,
    const float* __restrict__ h_prev,
    float* __restrict__ h_out,
    const float* __restrict__ wTx,
    const float* __restrict__ wTh,
    const float* __restrict__ b_ih,
    const float* __restrict__ b_hh,
    const int* __restrict__ lengths,
    int t)
{
    const int tid = threadIdx.x;
    const int cg = tid & 15;
    const int rg = tid >> 4;
    const int b  = blockIdx.x * 16 + rg;
    const int hc = blockIdx.y * 32 + (cg << 1);

    float accR0 = 0.f, accR1 = 0.f, accZ0 = 0.f, accZ1 = 0.f;
    float accXN0 = 0.f, accXN1 = 0.f, accHN0 = 0.f, accHN1 = 0.f;

    const float* xrow = x + ((size_t)t * BB + b) * DP1;
    const float2* wp = (const float2*)wTx + (hc >> 1);
    #pragma unroll 4
    for (int k = 0; k < DP1; ++k) {
        float a = xrow[k];
        float2 wr = wp[0];
        float2 wz = wp[256];
        float2 wn = wp[512];
        wp += 768;
        accR0 += a * wr.x; accR1 += a * wr.y;
        accZ0 += a * wz.x; accZ1 += a * wz.y;
        accXN0 += a * wn.x; accXN1 += a * wn.y;
    }

    const float* hrow = h_prev + (size_t)b * HH;
    const float2* wh = (const float2*)wTh + (hc >> 1);
    #pragma unroll 4
    for (int k = 0; k < HH; ++k) {
        float a = hrow[k];
        float2 wr = wh[0];
        float2 wz = wh[256];
        float2 wn = wh[512];
        wh += 768;
        accR0 += a * wr.x; accR1 += a * wr.y;
        accZ0 += a * wz.x; accZ1 += a * wz.y;
        accHN0 += a * wn.x; accHN1 += a * wn.y;
    }

    const bool valid = (t < lengths[b]);
    float* hout = h_out + (size_t)b * HH;
    {
        int j = hc;
        float rr = sigm(accR0 + b_ih[j] + b_hh[j]);
        float zz = sigm(accZ0 + b_ih[HH + j] + b_hh[HH + j]);
        float nn = tanhf(accXN0 + b_ih[2 * HH + j] + rr * (accHN0 + b_hh[2 * HH + j]));
        float hp = hrow[j];
        hout[j] = valid ? ((1.f - zz) * nn + zz * hp) : hp;
    }
    {
        int j = hc + 1;
        float rr = sigm(accR1 + b_ih[j] + b_hh[j]);
        float zz = sigm(accZ1 + b_ih[HH + j] + b_hh[HH + j]);
        float nn = tanhf(accXN1 + b_ih[2 * HH + j] + rr * (accHN1 + b_hh[2 * HH + j]));
        float hp = hrow[j];
        hout[j] = valid ? ((1.f - zz) * nn + zz * hp) : hp;
    }
}

// Fused 2-layer MLP head: per block 16 rows (r = b*255+t), loop kc in chunks of
// 256: stage1 (K=513 incl. td column) -> sigmoid -> LDS, stage2 accumulates
// preds (128 cols) in registers. No 'pre' matrix in HBM.
__global__ __launch_bounds__(256) void head_kernel(
    const float* __restrict__ x,
    const float* __restrict__ outs,
    const float* __restrict__ w1T,
    const float* __restrict__ w2T,
    const float* __restrict__ b1,
    const float* __restrict__ b2,
    const int* __restrict__ lengths,
    float* __restrict__ out)
{
    __shared__ float pre[16][260];
    const int tid = threadIdx.x;
    const int r0 = blockIdx.x * 16;

    const int cg = tid & 63;   // stage1: 64 col-groups x float4 = 256 kc
    const int rg = tid >> 6;   // stage1: rows rg, rg+4, rg+8, rg+12

    const float* arow[4];
    float tdv[4];
    #pragma unroll
    for (int i = 0; i < 4; ++i) {
        int r = r0 + rg + (i << 2);
        int b = r / 255;
        int t = r - b * 255;
        arow[i] = outs + ((size_t)t * BB + b) * HH;
        tdv[i] = x[((size_t)(t + 1) * BB + b) * DP1] - x[((size_t)t * BB + b) * DP1];
    }

    const int dg = tid & 31;   // stage2: d = dg*4
    const int rg2 = tid >> 5;  // stage2: rows rg2, rg2+8
    float acc2[2][4] = {{0.f, 0.f, 0.f, 0.f}, {0.f, 0.f, 0.f, 0.f}};

    const float4* w1T4 = (const float4*)w1T;
    const float4* w2T4 = (const float4*)w2T;

    for (int kcb = 0; kcb < K1; kcb += 256) {
        float4 s0 = {0, 0, 0, 0}, s1 = {0, 0, 0, 0}, s2 = {0, 0, 0, 0}, s3 = {0, 0, 0, 0};
        const int col4 = (kcb >> 2) + cg;
        #pragma unroll 2
        for (int k = 0; k < HH; ++k) {
            float4 w = w1T4[k * 320 + col4];
            float a0 = arow[0][k], a1v = arow[1][k], a2 = arow[2][k], a3 = arow[3][k];
            s0.x += a0 * w.x;  s0.y += a0 * w.y;  s0.z += a0 * w.z;  s0.w += a0 * w.w;
            s1.x += a1v * w.x; s1.y += a1v * w.y; s1.z += a1v * w.z; s1.w += a1v * w.w;
            s2.x += a2 * w.x;  s2.y += a2 * w.y;  s2.z += a2 * w.z;  s2.w += a2 * w.w;
            s3.x += a3 * w.x;  s3.y += a3 * w.y;  s3.z += a3 * w.z;  s3.w += a3 * w.w;
        }
        {   // td column (k = 512)
            float4 w = w1T4[512 * 320 + col4];
            s0.x += tdv[0] * w.x; s0.y += tdv[0] * w.y; s0.z += tdv[0] * w.z; s0.w += tdv[0] * w.w;
            s1.x += tdv[1] * w.x; s1.y += tdv[1] * w.y; s1.z += tdv[1] * w.z; s1.w += tdv[1] * w.w;
            s2.x += tdv[2] * w.x; s2.y += tdv[2] * w.y; s2.z += tdv[2] * w.z; s2.w += tdv[2] * w.w;
            s3.x += tdv[3] * w.x; s3.y += tdv[3] * w.y; s3.z += tdv[3] * w.z; s3.w += tdv[3] * w.w;
        }
        const int c = kcb + (cg << 2);
        float4 bb = *(const float4*)(b1 + c);
        float4 p;
        p.x = sigm(s0.x + bb.x); p.y = sigm(s0.y + bb.y); p.z = sigm(s0.z + bb.z); p.w = sigm(s0.w + bb.w);
        *(float4*)&pre[rg][cg << 2] = p;
        p.x = sigm(s1.x + bb.x); p.y = sigm(s1.y + bb.y); p.z = sigm(s1.z + bb.z); p.w = sigm(s1.w + bb.w);
        *(float4*)&pre[rg + 4][cg << 2] = p;
        p.x = sigm(s2.x + bb.x); p.y = sigm(s2.y + bb.y); p.z = sigm(s2.z + bb.z); p.w = sigm(s2.w + bb.w);
        *(float4*)&pre[rg + 8][cg << 2] = p;
        p.x = sigm(s3.x + bb.x); p.y = sigm(s3.y + bb.y); p.z = sigm(s3.z + bb.z); p.w = sigm(s3.w + bb.w);
        *(float4*)&pre[rg + 12][cg << 2] = p;
        __syncthreads();

        for (int kk = 0; kk < 256; kk += 4) {
            float4 p0 = *(const float4*)&pre[rg2][kk];
            float4 p1 = *(const float4*)&pre[rg2 + 8][kk];
            float pav[4] = {p0.x, p0.y, p0.z, p0.w};
            float pbv[4] = {p1.x, p1.y, p1.z, p1.w};
            #pragma unroll
            for (int i = 0; i < 4; ++i) {
                float4 w = w2T4[(size_t)(kcb + kk + i) * 32 + dg];
                float pa = pav[i], pb = pbv[i];
                acc2[0][0] += pa * w.x; acc2[0][1] += pa * w.y; acc2[0][2] += pa * w.z; acc2[0][3] += pa * w.w;
                acc2[1][0] += pb * w.x; acc2[1][1] += pb * w.y; acc2[1][2] += pb * w.z; acc2[1][3] += pb * w.w;
            }
        }
        __syncthreads();
    }

    #pragma unroll
    for (int u = 0; u < 2; ++u) {
        int r = r0 + rg2 + (u << 3);
        int b = r / 255;
        int t = r - b * 255;
        bool valid = t < (lengths[b] - 1);
        int d = dg << 2;
        float4 bb = *(const float4*)(b2 + d);
        float4 o;
        o.x = valid ? (acc2[u][0] + bb.x) : 0.f;
        o.y = valid ? (acc2[u][1] + bb.y) : 0.f;
        o.z = valid ? (acc2[u][2] + bb.z) : 0.f;
        o.w = valid ? (acc2[u][3] + bb.w) : 0.f;
        *(float4*)(out + (size_t)r * DD + d) = o;
    }
}

// dist_params = exp(-(h_last @ wp.T + bp)) and lengths passthrough (as float).
__global__ __launch_bounds__(256) void tail_kernel(
    const float* __restrict__ h_last,
    const float* __restrict__ wp,
    const float* __restrict__ bp,
    const int* __restrict__ lengths,
    float* __restrict__ out)
{
    int gid = blockIdx.x * 256 + threadIdx.x;
    if (gid < 768) {
        int b = gid / 3, p = gid - b * 3;
        float acc = bp[p];
        const float* hr = h_last + (size_t)b * HH;
        const float* wr = wp + (size_t)p * HH;
        #pragma unroll 4
        for (int k = 0; k < HH; ++k) acc += hr[k] * wr[k];
        out[OUT_DIST + gid] = __expf(-acc);
    } else if (gid < 1024) {
        int b = gid - 768;
        out[OUT_LEN + b] = (float)lengths[b];
    }
}

extern "C" void kernel_launch(void* const* d_in, const int* in_sizes, int n_in,
                              void* d_out, int out_size, void* d_ws, size_t ws_size,
                              hipStream_t stream)
{
    const float* x       = (const float*)d_in[0];
    const float* h0      = (const float*)d_in[1];
    const int*   lengths = (const int*)d_in[2];
    const float* w_ih    = (const float*)d_in[3];
    const float* w_hh    = (const float*)d_in[4];
    const float* b_ih    = (const float*)d_in[5];
    const float* b_hh    = (const float*)d_in[6];
    const float* w1      = (const float*)d_in[7];
    const float* b1      = (const float*)d_in[8];
    const float* w2      = (const float*)d_in[9];
    const float* b2      = (const float*)d_in[10];
    const float* wp      = (const float*)d_in[11];
    const float* bp      = (const float*)d_in[12];
    float* out = (float*)d_out;
    float* ws  = (float*)d_ws;

    float* wTx  = ws + OFF_WTX;
    float* wTh  = ws + OFF_WTH;
    float* w1T  = ws + OFF_W1T;
    float* w2T  = ws + OFF_W2T;
    float* outs = ws + OFF_OUTS;   // (T, B, H) hidden-state carries

    prep_kernel<<<7052, 256, 0, stream>>>(w_ih, w_hh, w1, w2, ws);

    for (int t = 0; t < TT; ++t) {
        const float* hp = (t == 0) ? h0 : (outs + (size_t)(t - 1) * BB * HH);
        gru_step<<<dim3(16, 16), 256, 0, stream>>>(
            x, hp, outs + (size_t)t * BB * HH, wTx, wTh, b_ih, b_hh, lengths, t);
    }

    head_kernel<<<RTOT / 16, 256, 0, stream>>>(x, outs, w1T, w2T, b1, b2, lengths, out);

    tail_kernel<<<4, 256, 0, stream>>>(outs + (size_t)(TT - 1) * BB * HH, wp, bp,
                                       lengths, out);
}

// Round 2
// 12133.717 us; speedup vs baseline: 1.7596x; 1.7596x over previous
//
#include <hip/hip_runtime.h>
#include <math.h>

#define TT 256
#define BB 256
#define DP1 129
#define HH 512
#define G3 1536
#define K1 1280
#define DD 128
#define RTOT 65280   // B*(T-1)

// ws layout (in floats)
#define OFF_WTX 0
#define OFF_WTH 198144       // 129*1536
#define OFF_W1T 984576       // +512*1536
#define OFF_W2T 1641216      // +513*1280
#define OFF_OUTS 1805056     // +1280*128
// out layout (floats)
#define OUT_DIST 8355840     // 256*255*128
#define OUT_LEN  8356608     // +256*3

__device__ __forceinline__ float sigm(float v) { return 1.0f / (1.0f + __expf(-v)); }

// Build k-major (transposed) copies of the weight matrices so GEMM-ish loops
// read W coalesced (lane = output column) and activations as LDS broadcast.
__global__ __launch_bounds__(256) void prep_kernel(
    const float* __restrict__ w_ih, const float* __restrict__ w_hh,
    const float* __restrict__ w1, const float* __restrict__ w2,
    float* __restrict__ ws)
{
    int i = blockIdx.x * 256 + threadIdx.x;
    if (i < 198144) {                       // wTx[k][j] = w_ih[j][k]
        int k = i / G3, j = i - k * G3;
        ws[OFF_WTX + i] = w_ih[j * DP1 + k];
    } else if (i < 984576) {                // wTh[k][j] = w_hh[j][k]
        int r = i - 198144;
        int k = r / G3, j = r - k * G3;
        ws[OFF_WTH + r] = w_hh[j * HH + k];
    } else if (i < 1641216) {               // w1T[k][kc] = w1[kc][k]
        int r = i - 984576;
        int k = r / K1, kc = r - k * K1;
        ws[OFF_W1T + r] = w1[kc * 513 + k];
    } else if (i < 1805056) {               // w2T[kc][d] = w2[d][kc]
        int r = i - 1641216;
        int kc = r / DD, d = r - kc * DD;
        ws[OFF_W2T + r] = w2[d * K1 + kc];
    }
}

// One GRU timestep. K-split design: block = 512 threads = 8 waves.
// Wave w handles K-chunk w (K = 129 x-part + 512 h-part = 641, split ~80/wave,
// wave-uniform). Thread = (batch b of 16, col-quad cq of 4, chunk kc of 8),
// 16 accumulators (4 cols x {r,z,xn,hn}; xn/hn separate so r*hn is exact).
// Partials -> LDS -> 256 threads reduce + gates + carry.
// grid (16 batch-blocks, 32 col-blocks) = 512 blocks = 2/CU = 4 waves/SIMD.
__global__ __launch_bounds__(512, 4) void gru_step2(
    const float* __restrict__ x,
    const float* __restrict__ h_prev,
    float* __restrict__ h_out,
    const float* __restrict__ wTx,
    const float* __restrict__ wTh,
    const float* __restrict__ b_ih,
    const float* __restrict__ b_hh,
    const int* __restrict__ lengths,
    int t)
{
    __shared__ float hs[16 * 516];            // h tile, stride 516 (2-way banks = free)
    __shared__ float xs[16 * 132];            // x tile, stride 132
    __shared__ float red[8][16][16][4];       // [kc][b][col][{r,z,xn,hn}]

    const int tid  = threadIdx.x;
    const int b0   = blockIdx.x * 16;
    const int cblk = blockIdx.y;              // 16 h-cols per block

    // stage h_prev tile (16 rows x 512 floats, contiguous source)
    {
        const float4* src = (const float4*)(h_prev + (size_t)b0 * HH);
        float4* dst = (float4*)hs;
        #pragma unroll
        for (int i = 0; i < 4; ++i) {
            int i4 = tid + i * 512;           // 2048 float4 total
            int bb = i4 >> 7, kq = i4 & 127;  // 128 float4 per row
            dst[bb * 129 + kq] = src[i4];     // 129 float4 = 516 floats stride
        }
    }
    // stage x tile (16 rows x 129 floats)
    for (int i = tid; i < 16 * DP1; i += 512) {
        int bb = i / DP1, k = i - bb * DP1;
        xs[bb * 132 + k] = x[((size_t)t * BB + b0 + bb) * DP1 + k];
    }
    __syncthreads();

    const int kc = tid >> 6;                  // wave-uniform chunk id
    const int ln = tid & 63;
    const int b  = ln >> 2;                   // 0..15
    const int cq = ln & 3;                    // 0..3 -> local cols cq*4..cq*4+3
    const int hq = (cblk * 16 + cq * 4) >> 2; // float4 col index (of 384)

    const int lo = (641 * kc) >> 3;
    const int hi = (641 * (kc + 1)) >> 3;

    float aR[4] = {0,0,0,0}, aZ[4] = {0,0,0,0};
    float aXN[4] = {0,0,0,0}, aHN[4] = {0,0,0,0};

    const float4* w4x = (const float4*)wTx;
    const float4* w4h = (const float4*)wTh;

    // x segment: k in [lo, min(hi,129))
    const int xend = (hi < DP1) ? hi : DP1;
    #pragma unroll 4
    for (int k = lo; k < xend; ++k) {
        float a = xs[b * 132 + k];
        float4 wr = w4x[k * 384 + hq];
        float4 wz = w4x[k * 384 + hq + 128];
        float4 wn = w4x[k * 384 + hq + 256];
        aR[0] += a * wr.x; aR[1] += a * wr.y; aR[2] += a * wr.z; aR[3] += a * wr.w;
        aZ[0] += a * wz.x; aZ[1] += a * wz.y; aZ[2] += a * wz.z; aZ[3] += a * wz.w;
        aXN[0] += a * wn.x; aXN[1] += a * wn.y; aXN[2] += a * wn.z; aXN[3] += a * wn.w;
    }
    // h segment: k in [max(lo,129), hi)
    const int hstart = (lo > DP1) ? lo : DP1;
    #pragma unroll 4
    for (int k = hstart; k < hi; ++k) {
        int kk = k - DP1;
        float a = hs[b * 516 + kk];
        float4 wr = w4h[kk * 384 + hq];
        float4 wz = w4h[kk * 384 + hq + 128];
        float4 wn = w4h[kk * 384 + hq + 256];
        aR[0] += a * wr.x; aR[1] += a * wr.y; aR[2] += a * wr.z; aR[3] += a * wr.w;
        aZ[0] += a * wz.x; aZ[1] += a * wz.y; aZ[2] += a * wz.z; aZ[3] += a * wz.w;
        aHN[0] += a * wn.x; aHN[1] += a * wn.y; aHN[2] += a * wn.z; aHN[3] += a * wn.w;
    }

    #pragma unroll
    for (int c = 0; c < 4; ++c) {
        int lc = cq * 4 + c;
        red[kc][b][lc][0] = aR[c];
        red[kc][b][lc][1] = aZ[c];
        red[kc][b][lc][2] = aXN[c];
        red[kc][b][lc][3] = aHN[c];
    }
    __syncthreads();

    if (tid < 256) {
        const int rb = tid >> 4;              // 0..15
        const int col = tid & 15;             // 0..15
        float sR = 0.f, sZ = 0.f, sXN = 0.f, sHN = 0.f;
        #pragma unroll
        for (int c = 0; c < 8; ++c) {
            sR  += red[c][rb][col][0];
            sZ  += red[c][rb][col][1];
            sXN += red[c][rb][col][2];
            sHN += red[c][rb][col][3];
        }
        const int j = cblk * 16 + col;        // global h index
        float rr = sigm(sR + b_ih[j] + b_hh[j]);
        float zz = sigm(sZ + b_ih[HH + j] + b_hh[HH + j]);
        float nn = tanhf(sXN + b_ih[2 * HH + j] + rr * (sHN + b_hh[2 * HH + j]));
        float hp = hs[rb * 516 + j];
        bool valid = (t < lengths[b0 + rb]);
        h_out[(size_t)(b0 + rb) * HH + j] = valid ? ((1.f - zz) * nn + zz * hp) : hp;
    }
}

// Fused 2-layer MLP head: per block 16 rows (r = b*255+t), loop kc in chunks of
// 256: stage1 (K=513 incl. td column) -> sigmoid -> LDS, stage2 accumulates
// preds (128 cols) in registers. No 'pre' matrix in HBM.
__global__ __launch_bounds__(256) void head_kernel(
    const float* __restrict__ x,
    const float* __restrict__ outs,
    const float* __restrict__ w1T,
    const float* __restrict__ w2T,
    const float* __restrict__ b1,
    const float* __restrict__ b2,
    const int* __restrict__ lengths,
    float* __restrict__ out)
{
    __shared__ float pre[16][260];
    const int tid = threadIdx.x;
    const int r0 = blockIdx.x * 16;

    const int cg = tid & 63;   // stage1: 64 col-groups x float4 = 256 kc
    const int rg = tid >> 6;   // stage1: rows rg, rg+4, rg+8, rg+12

    const float* arow[4];
    float tdv[4];
    #pragma unroll
    for (int i = 0; i < 4; ++i) {
        int r = r0 + rg + (i << 2);
        int b = r / 255;
        int t = r - b * 255;
        arow[i] = outs + ((size_t)t * BB + b) * HH;
        tdv[i] = x[((size_t)(t + 1) * BB + b) * DP1] - x[((size_t)t * BB + b) * DP1];
    }

    const int dg = tid & 31;   // stage2: d = dg*4
    const int rg2 = tid >> 5;  // stage2: rows rg2, rg2+8
    float acc2[2][4] = {{0.f, 0.f, 0.f, 0.f}, {0.f, 0.f, 0.f, 0.f}};

    const float4* w1T4 = (const float4*)w1T;
    const float4* w2T4 = (const float4*)w2T;

    for (int kcb = 0; kcb < K1; kcb += 256) {
        float4 s0 = {0, 0, 0, 0}, s1 = {0, 0, 0, 0}, s2 = {0, 0, 0, 0}, s3 = {0, 0, 0, 0};
        const int col4 = (kcb >> 2) + cg;
        #pragma unroll 2
        for (int k = 0; k < HH; ++k) {
            float4 w = w1T4[k * 320 + col4];
            float a0 = arow[0][k], a1v = arow[1][k], a2 = arow[2][k], a3 = arow[3][k];
            s0.x += a0 * w.x;  s0.y += a0 * w.y;  s0.z += a0 * w.z;  s0.w += a0 * w.w;
            s1.x += a1v * w.x; s1.y += a1v * w.y; s1.z += a1v * w.z; s1.w += a1v * w.w;
            s2.x += a2 * w.x;  s2.y += a2 * w.y;  s2.z += a2 * w.z;  s2.w += a2 * w.w;
            s3.x += a3 * w.x;  s3.y += a3 * w.y;  s3.z += a3 * w.z;  s3.w += a3 * w.w;
        }
        {   // td column (k = 512)
            float4 w = w1T4[512 * 320 + col4];
            s0.x += tdv[0] * w.x; s0.y += tdv[0] * w.y; s0.z += tdv[0] * w.z; s0.w += tdv[0] * w.w;
            s1.x += tdv[1] * w.x; s1.y += tdv[1] * w.y; s1.z += tdv[1] * w.z; s1.w += tdv[1] * w.w;
            s2.x += tdv[2] * w.x; s2.y += tdv[2] * w.y; s2.z += tdv[2] * w.z; s2.w += tdv[2] * w.w;
            s3.x += tdv[3] * w.x; s3.y += tdv[3] * w.y; s3.z += tdv[3] * w.z; s3.w += tdv[3] * w.w;
        }
        const int c = kcb + (cg << 2);
        float4 bb = *(const float4*)(b1 + c);
        float4 p;
        p.x = sigm(s0.x + bb.x); p.y = sigm(s0.y + bb.y); p.z = sigm(s0.z + bb.z); p.w = sigm(s0.w + bb.w);
        *(float4*)&pre[rg][cg << 2] = p;
        p.x = sigm(s1.x + bb.x); p.y = sigm(s1.y + bb.y); p.z = sigm(s1.z + bb.z); p.w = sigm(s1.w + bb.w);
        *(float4*)&pre[rg + 4][cg << 2] = p;
        p.x = sigm(s2.x + bb.x); p.y = sigm(s2.y + bb.y); p.z = sigm(s2.z + bb.z); p.w = sigm(s2.w + bb.w);
        *(float4*)&pre[rg + 8][cg << 2] = p;
        p.x = sigm(s3.x + bb.x); p.y = sigm(s3.y + bb.y); p.z = sigm(s3.z + bb.z); p.w = sigm(s3.w + bb.w);
        *(float4*)&pre[rg + 12][cg << 2] = p;
        __syncthreads();

        for (int kk = 0; kk < 256; kk += 4) {
            float4 p0 = *(const float4*)&pre[rg2][kk];
            float4 p1 = *(const float4*)&pre[rg2 + 8][kk];
            float pav[4] = {p0.x, p0.y, p0.z, p0.w};
            float pbv[4] = {p1.x, p1.y, p1.z, p1.w};
            #pragma unroll
            for (int i = 0; i < 4; ++i) {
                float4 w = w2T4[(size_t)(kcb + kk + i) * 32 + dg];
                float pa = pav[i], pb = pbv[i];
                acc2[0][0] += pa * w.x; acc2[0][1] += pa * w.y; acc2[0][2] += pa * w.z; acc2[0][3] += pa * w.w;
                acc2[1][0] += pb * w.x; acc2[1][1] += pb * w.y; acc2[1][2] += pb * w.z; acc2[1][3] += pb * w.w;
            }
        }
        __syncthreads();
    }

    #pragma unroll
    for (int u = 0; u < 2; ++u) {
        int r = r0 + rg2 + (u << 3);
        int b = r / 255;
        int t = r - b * 255;
        bool valid = t < (lengths[b] - 1);
        int d = dg << 2;
        float4 bb = *(const float4*)(b2 + d);
        float4 o;
        o.x = valid ? (acc2[u][0] + bb.x) : 0.f;
        o.y = valid ? (acc2[u][1] + bb.y) : 0.f;
        o.z = valid ? (acc2[u][2] + bb.z) : 0.f;
        o.w = valid ? (acc2[u][3] + bb.w) : 0.f;
        *(float4*)(out + (size_t)r * DD + d) = o;
    }
}

// dist_params = exp(-(h_last @ wp.T + bp)) and lengths passthrough (as float).
__global__ __launch_bounds__(256) void tail_kernel(
    const float* __restrict__ h_last,
    const float* __restrict__ wp,
    const float* __restrict__ bp,
    const int* __restrict__ lengths,
    float* __restrict__ out)
{
    int gid = blockIdx.x * 256 + threadIdx.x;
    if (gid < 768) {
        int b = gid / 3, p = gid - b * 3;
        float acc = bp[p];
        const float* hr = h_last + (size_t)b * HH;
        const float* wr = wp + (size_t)p * HH;
        #pragma unroll 4
        for (int k = 0; k < HH; ++k) acc += hr[k] * wr[k];
        out[OUT_DIST + gid] = __expf(-acc);
    } else if (gid < 1024) {
        int b = gid - 768;
        out[OUT_LEN + b] = (float)lengths[b];
    }
}

extern "C" void kernel_launch(void* const* d_in, const int* in_sizes, int n_in,
                              void* d_out, int out_size, void* d_ws, size_t ws_size,
                              hipStream_t stream)
{
    const float* x       = (const float*)d_in[0];
    const float* h0      = (const float*)d_in[1];
    const int*   lengths = (const int*)d_in[2];
    const float* w_ih    = (const float*)d_in[3];
    const float* w_hh    = (const float*)d_in[4];
    const float* b_ih    = (const float*)d_in[5];
    const float* b_hh    = (const float*)d_in[6];
    const float* w1      = (const float*)d_in[7];
    const float* b1      = (const float*)d_in[8];
    const float* w2      = (const float*)d_in[9];
    const float* b2      = (const float*)d_in[10];
    const float* wp      = (const float*)d_in[11];
    const float* bp      = (const float*)d_in[12];
    float* out = (float*)d_out;
    float* ws  = (float*)d_ws;

    float* wTx  = ws + OFF_WTX;
    float* wTh  = ws + OFF_WTH;
    float* w1T  = ws + OFF_W1T;
    float* w2T  = ws + OFF_W2T;
    float* outs = ws + OFF_OUTS;   // (T, B, H) hidden-state carries

    prep_kernel<<<7052, 256, 0, stream>>>(w_ih, w_hh, w1, w2, ws);

    for (int t = 0; t < TT; ++t) {
        const float* hp = (t == 0) ? h0 : (outs + (size_t)(t - 1) * BB * HH);
        gru_step2<<<dim3(16, 32), 512, 0, stream>>>(
            x, hp, outs + (size_t)t * BB * HH, wTx, wTh, b_ih, b_hh, lengths, t);
    }

    head_kernel<<<RTOT / 16, 256, 0, stream>>>(x, outs, w1T, w2T, b1, b2, lengths, out);

    tail_kernel<<<4, 256, 0, stream>>>(outs + (size_t)(TT - 1) * BB * HH, wp, bp,
                                       lengths, out);
}

// Round 3
// 5458.119 us; speedup vs baseline: 3.9118x; 2.2231x over previous
//
#include <hip/hip_runtime.h>
#include <hip/hip_bf16.h>
#include <math.h>

#define TT 256
#define BB 256
#define DP1 129
#define HH 512
#define K1 1280
#define DD 128
#define RTOT 65280   // B*(T-1)
#define XKP 144      // padded x-part K (129 feats + 1 bias + 14 zero)
#define HKP 528      // padded h-part K (512 h + 1 bias + 15 zero)

// ---- ws layout ----
// float region:
#define OFF_W1T 0            // 513*1280
#define OFF_W2T 656640       // 1280*128
#define F_END   820480
// bf16 region (offsets in elements, base = (bf16*)(ws + F_END)):
#define U_X16   0            // 65536*144
#define U_WHF   9437184      // 48*33*512   (16 jblk * 3 gate, 33 kchunks, 64 lanes * 8)
#define U_WXF   10248192     // 48*9*512
#define U_H0    10469376     // 256*528
#define U_HIST  10604544     // 256*256*528
// out layout (floats)
#define OUT_DIST 8355840     // 256*255*128
#define OUT_LEN  8356608

typedef __attribute__((ext_vector_type(8))) short bf16x8;
typedef __attribute__((ext_vector_type(16))) float f32x16;

__device__ __forceinline__ float sigm(float v) { return 1.0f / (1.0f + __expf(-v)); }

// One-time pack: fp32 head weights transposed + bf16 x (with bias col) +
// GRU weights in exact MFMA B-fragment order (lane-contiguous) + h0.
__global__ __launch_bounds__(256) void prep_kernel(
    const float* __restrict__ x, const float* __restrict__ h0,
    const float* __restrict__ w_ih, const float* __restrict__ w_hh,
    const float* __restrict__ b_ih, const float* __restrict__ b_hh,
    const float* __restrict__ w1, const float* __restrict__ w2,
    float* __restrict__ ws)
{
    __hip_bfloat16* bf = (__hip_bfloat16*)(ws + F_END);
    int i = blockIdx.x * 256 + threadIdx.x;
    if (i < 656640) {                         // w1T[k][kc] = w1[kc][k]
        int k = i / K1, kc = i - k * K1;
        ws[OFF_W1T + i] = w1[kc * 513 + k];
    } else if (i < 820480) {                  // w2T[kc][d] = w2[d][kc]
        int r = i - 656640;
        int kc = r / DD, d = r - kc * DD;
        ws[OFF_W2T + r] = w2[d * K1 + kc];
    } else if (i < 10257664) {                // x16: (t*B+b, 144)
        int r = i - 820480;
        int tb = r / XKP, k = r - tb * XKP;
        float v = (k < DP1) ? x[(size_t)tb * DP1 + k] : (k == DP1 ? 1.0f : 0.0f);
        bf[U_X16 + r] = __float2bfloat16(v);
    } else if (i < 11068672) {                // whf B-frags (K=528 incl b_hh row)
        int r = i - 10257664;
        int e = r & 7;
        int lane = (r >> 3) & 63;
        int rem = r >> 9;
        int kc = rem % 33, gi = rem / 33;
        int jb = gi / 3, g = gi - jb * 3;
        int j = jb * 32 + (lane & 31);
        int k = kc * 16 + (lane >> 5) * 8 + e;
        float v = (k < HH) ? w_hh[(size_t)(g * HH + j) * HH + k]
                : (k == HH ? b_hh[g * HH + j] : 0.0f);
        bf[U_WHF + r] = __float2bfloat16(v);
    } else if (i < 11289856) {                // wxf B-frags (K=144 incl b_ih row)
        int r = i - 11068672;
        int e = r & 7;
        int lane = (r >> 3) & 63;
        int rem = r >> 9;
        int kc = rem % 9, gi = rem / 9;
        int jb = gi / 3, g = gi - jb * 3;
        int j = jb * 32 + (lane & 31);
        int k = kc * 16 + (lane >> 5) * 8 + e;
        float v = (k < DP1) ? w_ih[(size_t)(g * HH + j) * DP1 + k]
                : (k == DP1 ? b_ih[g * HH + j] : 0.0f);
        bf[U_WXF + r] = __float2bfloat16(v);
    } else if (i < 11425024) {                // h0 padded (B, 528)
        int r = i - 11289856;
        int b = r / HKP, k = r - b * HKP;
        float v = (k < HH) ? h0[(size_t)b * HH + k] : (k == HH ? 1.0f : 0.0f);
        bf[U_H0 + r] = __float2bfloat16(v);
    }
}

// One GRU step via bf16 MFMA. Block = 32 batch x 32 h-cols; waves 0/1/2
// compute gate r/z/n preacts (x-part K=144 + h-part K=528, biases folded as
// constant-1 K columns); preacts exchanged via LDS; all 4 waves run the
// gate/carry epilogue. Grid (8,16) = 128 blocks.
__global__ __launch_bounds__(256) void gru_step3(
    const __hip_bfloat16* __restrict__ x16,
    const __hip_bfloat16* __restrict__ hprev,   // (B, 528)
    __hip_bfloat16* __restrict__ hout,          // (B, 528)
    const __hip_bfloat16* __restrict__ whf,
    const __hip_bfloat16* __restrict__ wxf,
    const int* __restrict__ lengths,
    int t)
{
    __shared__ float p[4][32][33];   // r, z, xn, hn preacts (+1 pad col)
    const int tid = threadIdx.x;
    const int b0 = blockIdx.x * 32;
    const int jblk = blockIdx.y;
    const int wid = tid >> 6;
    const int ln = tid & 63;

    if (wid < 3) {
        f32x16 accH = {};
        f32x16 accX = {};
        const int row = b0 + (ln & 31);
        const int khi = (ln >> 5) * 8;

        // h-part: K = 528 (33 chunks)
        const bf16x8* aH = (const bf16x8*)(hprev + (size_t)row * HKP + khi);
        const bf16x8* bH = (const bf16x8*)whf + ((jblk * 3 + wid) * 33) * 64 + ln;
        #pragma unroll 4
        for (int kc = 0; kc < 33; ++kc) {
            bf16x8 a = aH[kc * 2];
            bf16x8 b = bH[(size_t)kc * 64];
            accH = __builtin_amdgcn_mfma_f32_32x32x16_bf16(a, b, accH, 0, 0, 0);
        }
        // x-part: K = 144 (9 chunks)
        const bf16x8* aX = (const bf16x8*)(x16 + ((size_t)t * BB + row) * XKP + khi);
        const bf16x8* bX = (const bf16x8*)wxf + ((jblk * 3 + wid) * 9) * 64 + ln;
        #pragma unroll
        for (int kc = 0; kc < 9; ++kc) {
            bf16x8 a = aX[kc * 2];
            bf16x8 b = bX[(size_t)kc * 64];
            accX = __builtin_amdgcn_mfma_f32_32x32x16_bf16(a, b, accX, 0, 0, 0);
        }

        const int col = ln & 31;
        const int rh = 4 * (ln >> 5);
        if (wid < 2) {
            f32x16 s = accH + accX;
            #pragma unroll
            for (int r = 0; r < 16; ++r) {
                int rr = (r & 3) + 8 * (r >> 2) + rh;
                p[wid][rr][col] = s[r];
            }
        } else {
            #pragma unroll
            for (int r = 0; r < 16; ++r) {
                int rr = (r & 3) + 8 * (r >> 2) + rh;
                p[2][rr][col] = accX[r];   // xn (+ b_ih_n)
                p[3][rr][col] = accH[r];   // hn (+ b_hh_n)
            }
        }
    }
    __syncthreads();

    const int j = tid & 31;
    const int r0 = tid >> 5;          // 0..7
    const int gj = jblk * 32 + j;
    #pragma unroll
    for (int u = 0; u < 4; ++u) {
        int br = r0 + u * 8;
        int b = b0 + br;
        float rr = sigm(p[0][br][j]);
        float zz = sigm(p[1][br][j]);
        float nn = tanhf(p[2][br][j] + rr * p[3][br][j]);
        float hp = __bfloat162float(hprev[(size_t)b * HKP + gj]);
        bool valid = (t < lengths[b]);
        float hn = valid ? ((1.f - zz) * nn + zz * hp) : hp;
        hout[(size_t)b * HKP + gj] = __float2bfloat16(hn);
    }
    if (jblk == 0) {                  // bias-1 + zero pad cols 512..527
        int br = tid >> 3;
        int c = (tid & 7) * 2;
        hout[(size_t)(b0 + br) * HKP + HH + c]     = __float2bfloat16(c == 0 ? 1.0f : 0.0f);
        hout[(size_t)(b0 + br) * HKP + HH + c + 1] = __float2bfloat16(0.0f);
    }
}

// Fused 2-layer MLP head (fp32 compute, bf16 hidden-state reads).
__global__ __launch_bounds__(256) void head_kernel(
    const float* __restrict__ x,
    const __hip_bfloat16* __restrict__ hist,
    const float* __restrict__ w1T,
    const float* __restrict__ w2T,
    const float* __restrict__ b1,
    const float* __restrict__ b2,
    const int* __restrict__ lengths,
    float* __restrict__ out)
{
    __shared__ float pre[16][260];
    const int tid = threadIdx.x;
    const int r0 = blockIdx.x * 16;

    const int cg = tid & 63;
    const int rg = tid >> 6;

    const __hip_bfloat16* arow[4];
    float tdv[4];
    #pragma unroll
    for (int i = 0; i < 4; ++i) {
        int r = r0 + rg + (i << 2);
        int b = r / 255;
        int t = r - b * 255;
        arow[i] = hist + ((size_t)t * BB + b) * HKP;
        tdv[i] = x[((size_t)(t + 1) * BB + b) * DP1] - x[((size_t)t * BB + b) * DP1];
    }

    const int dg = tid & 31;
    const int rg2 = tid >> 5;
    float acc2[2][4] = {{0.f, 0.f, 0.f, 0.f}, {0.f, 0.f, 0.f, 0.f}};

    const float4* w1T4 = (const float4*)w1T;
    const float4* w2T4 = (const float4*)w2T;

    for (int kcb = 0; kcb < K1; kcb += 256) {
        float4 s0 = {0, 0, 0, 0}, s1 = {0, 0, 0, 0}, s2 = {0, 0, 0, 0}, s3 = {0, 0, 0, 0};
        const int col4 = (kcb >> 2) + cg;
        #pragma unroll 2
        for (int k = 0; k < HH; ++k) {
            float4 w = w1T4[k * 320 + col4];
            float a0 = __bfloat162float(arow[0][k]);
            float a1v = __bfloat162float(arow[1][k]);
            float a2 = __bfloat162float(arow[2][k]);
            float a3 = __bfloat162float(arow[3][k]);
            s0.x += a0 * w.x;  s0.y += a0 * w.y;  s0.z += a0 * w.z;  s0.w += a0 * w.w;
            s1.x += a1v * w.x; s1.y += a1v * w.y; s1.z += a1v * w.z; s1.w += a1v * w.w;
            s2.x += a2 * w.x;  s2.y += a2 * w.y;  s2.z += a2 * w.z;  s2.w += a2 * w.w;
            s3.x += a3 * w.x;  s3.y += a3 * w.y;  s3.z += a3 * w.z;  s3.w += a3 * w.w;
        }
        {   // td column (k = 512)
            float4 w = w1T4[512 * 320 + col4];
            s0.x += tdv[0] * w.x; s0.y += tdv[0] * w.y; s0.z += tdv[0] * w.z; s0.w += tdv[0] * w.w;
            s1.x += tdv[1] * w.x; s1.y += tdv[1] * w.y; s1.z += tdv[1] * w.z; s1.w += tdv[1] * w.w;
            s2.x += tdv[2] * w.x; s2.y += tdv[2] * w.y; s2.z += tdv[2] * w.z; s2.w += tdv[2] * w.w;
            s3.x += tdv[3] * w.x; s3.y += tdv[3] * w.y; s3.z += tdv[3] * w.z; s3.w += tdv[3] * w.w;
        }
        const int c = kcb + (cg << 2);
        float4 bb = *(const float4*)(b1 + c);
        float4 pv;
        pv.x = sigm(s0.x + bb.x); pv.y = sigm(s0.y + bb.y); pv.z = sigm(s0.z + bb.z); pv.w = sigm(s0.w + bb.w);
        *(float4*)&pre[rg][cg << 2] = pv;
        pv.x = sigm(s1.x + bb.x); pv.y = sigm(s1.y + bb.y); pv.z = sigm(s1.z + bb.z); pv.w = sigm(s1.w + bb.w);
        *(float4*)&pre[rg + 4][cg << 2] = pv;
        pv.x = sigm(s2.x + bb.x); pv.y = sigm(s2.y + bb.y); pv.z = sigm(s2.z + bb.z); pv.w = sigm(s2.w + bb.w);
        *(float4*)&pre[rg + 8][cg << 2] = pv;
        pv.x = sigm(s3.x + bb.x); pv.y = sigm(s3.y + bb.y); pv.z = sigm(s3.z + bb.z); pv.w = sigm(s3.w + bb.w);
        *(float4*)&pre[rg + 12][cg << 2] = pv;
        __syncthreads();

        for (int kk = 0; kk < 256; kk += 4) {
            float4 p0 = *(const float4*)&pre[rg2][kk];
            float4 p1 = *(const float4*)&pre[rg2 + 8][kk];
            float pav[4] = {p0.x, p0.y, p0.z, p0.w};
            float pbv[4] = {p1.x, p1.y, p1.z, p1.w};
            #pragma unroll
            for (int i = 0; i < 4; ++i) {
                float4 w = w2T4[(size_t)(kcb + kk + i) * 32 + dg];
                float pa = pav[i], pb = pbv[i];
                acc2[0][0] += pa * w.x; acc2[0][1] += pa * w.y; acc2[0][2] += pa * w.z; acc2[0][3] += pa * w.w;
                acc2[1][0] += pb * w.x; acc2[1][1] += pb * w.y; acc2[1][2] += pb * w.z; acc2[1][3] += pb * w.w;
            }
        }
        __syncthreads();
    }

    #pragma unroll
    for (int u = 0; u < 2; ++u) {
        int r = r0 + rg2 + (u << 3);
        int b = r / 255;
        int t = r - b * 255;
        bool valid = t < (lengths[b] - 1);
        int d = dg << 2;
        float4 bb = *(const float4*)(b2 + d);
        float4 o;
        o.x = valid ? (acc2[u][0] + bb.x) : 0.f;
        o.y = valid ? (acc2[u][1] + bb.y) : 0.f;
        o.z = valid ? (acc2[u][2] + bb.z) : 0.f;
        o.w = valid ? (acc2[u][3] + bb.w) : 0.f;
        *(float4*)(out + (size_t)r * DD + d) = o;
    }
}

__global__ __launch_bounds__(256) void tail_kernel(
    const __hip_bfloat16* __restrict__ hist,
    const float* __restrict__ wp,
    const float* __restrict__ bp,
    const int* __restrict__ lengths,
    float* __restrict__ out)
{
    int gid = blockIdx.x * 256 + threadIdx.x;
    if (gid < 768) {
        int b = gid / 3, pidx = gid - b * 3;
        float acc = bp[pidx];
        const __hip_bfloat16* hr = hist + ((size_t)(TT - 1) * BB + b) * HKP;
        const float* wr = wp + (size_t)pidx * HH;
        #pragma unroll 4
        for (int k = 0; k < HH; ++k) acc += __bfloat162float(hr[k]) * wr[k];
        out[OUT_DIST + gid] = __expf(-acc);
    } else if (gid < 1024) {
        int b = gid - 768;
        out[OUT_LEN + b] = (float)lengths[b];
    }
}

extern "C" void kernel_launch(void* const* d_in, const int* in_sizes, int n_in,
                              void* d_out, int out_size, void* d_ws, size_t ws_size,
                              hipStream_t stream)
{
    const float* x       = (const float*)d_in[0];
    const float* h0      = (const float*)d_in[1];
    const int*   lengths = (const int*)d_in[2];
    const float* w_ih    = (const float*)d_in[3];
    const float* w_hh    = (const float*)d_in[4];
    const float* b_ih    = (const float*)d_in[5];
    const float* b_hh    = (const float*)d_in[6];
    const float* w1      = (const float*)d_in[7];
    const float* b1      = (const float*)d_in[8];
    const float* w2      = (const float*)d_in[9];
    const float* b2      = (const float*)d_in[10];
    const float* wp      = (const float*)d_in[11];
    const float* bp      = (const float*)d_in[12];
    float* out = (float*)d_out;
    float* ws  = (float*)d_ws;

    __hip_bfloat16* bf   = (__hip_bfloat16*)(ws + F_END);
    __hip_bfloat16* x16  = bf + U_X16;
    __hip_bfloat16* whf  = bf + U_WHF;
    __hip_bfloat16* wxf  = bf + U_WXF;
    __hip_bfloat16* h16i = bf + U_H0;
    __hip_bfloat16* hist = bf + U_HIST;

    prep_kernel<<<44629, 256, 0, stream>>>(x, h0, w_ih, w_hh, b_ih, b_hh, w1, w2, ws);

    for (int t = 0; t < TT; ++t) {
        const __hip_bfloat16* hp = (t == 0) ? h16i : (hist + (size_t)(t - 1) * BB * HKP);
        gru_step3<<<dim3(8, 16), 256, 0, stream>>>(
            x16, hp, hist + (size_t)t * BB * HKP, whf, wxf, lengths, t);
    }

    head_kernel<<<RTOT / 16, 256, 0, stream>>>(x, hist, ws + OFF_W1T, ws + OFF_W2T,
                                               b1, b2, lengths, out);

    tail_kernel<<<4, 256, 0, stream>>>(hist, wp, bp, lengths, out);
}